// Round 14
// baseline (2671.871 us; speedup 1.0000x reference)
//
#include <hip/hip_runtime.h>
#include <hip/hip_bf16.h>
#include <math.h>

#define T_STEPS 256
#define NBLK    128

typedef __attribute__((ext_vector_type(8))) short short8_t;   // 8 bf16
typedef __attribute__((ext_vector_type(4))) float f32x4;
typedef __attribute__((ext_vector_type(4))) unsigned short ushort4_t;

__device__ __forceinline__ unsigned short f2bf(float v) {
    __hip_bfloat16 h = __float2bfloat16(v);
    return *reinterpret_cast<unsigned short*>(&h);
}
__device__ __forceinline__ float bf2f(unsigned short u) {
    __hip_bfloat16 h;
    *reinterpret_cast<unsigned short*>(&h) = u;
    return __bfloat162float(h);
}

// ---------------------------------------------------------------------------
// pack_gate: gate-weight B-fragments for 128-block layout, bf16 hi/lo.
// ---------------------------------------------------------------------------
__global__ __launch_bounds__(256) void pack_gate(
    const float* __restrict__ Wi, const float* __restrict__ Wf,
    const float* __restrict__ Wo, const float* __restrict__ Wc,
    unsigned short* __restrict__ PGh, unsigned short* __restrict__ PGl)
{
    int ng = blockIdx.y;
    int slot = blockIdx.x * 4 + (threadIdx.x >> 6);   // 0..63
    int nt = slot >> 5, ks = slot & 31;
    int lane = threadIdx.x & 63;
    int n = lane & 15, g = n >> 2;
    int j = 8 * ng + nt * 4 + (n & 3);
    int k0 = ks * 32 + (lane >> 4) * 8;
    const float* W = (g == 0) ? Wi : (g == 1) ? Wf : (g == 2) ? Wo : Wc;
    const float* src = W + (size_t)j * 1024 + k0;

    union { short8_t v; unsigned short u[8]; } hi, lo;
#pragma unroll
    for (int e = 0; e < 8; ++e) {
        float v = src[e];
        hi.u[e] = f2bf(v);
        lo.u[e] = f2bf(v - bf2f(hi.u[e]));
    }
    size_t o = (((size_t)(ng * 2 + nt) * 32 + ks) * 64 + lane) * 8;
    *(short8_t*)(PGh + o) = hi.v;
    *(short8_t*)(PGl + o) = lo.v;
}

// ---------------------------------------------------------------------------
// pack_out: compact out-weight frags (8 real cols per block).
// ---------------------------------------------------------------------------
__global__ __launch_bounds__(256) void pack_out(
    const float* __restrict__ Wout,
    unsigned short* __restrict__ POh, unsigned short* __restrict__ POl)
{
    int ng = blockIdx.y;
    int ks = blockIdx.x * 8 + (threadIdx.x >> 5);
    int sl = threadIdx.x & 31;
    int kb = sl >> 3, n = sl & 7;
    int j = 8 * ng + n;
    int k0 = ks * 32 + kb * 8;
    const float* src = Wout + (size_t)j * 1024 + k0;

    union { short8_t v; unsigned short u[8]; } hi, lo;
#pragma unroll
    for (int e = 0; e < 8; ++e) {
        float v = src[e];
        hi.u[e] = f2bf(v);
        lo.u[e] = f2bf(v - bf2f(hi.u[e]));
    }
    size_t o = (((size_t)ng * 32 + ks) * 32 + sl) * 8;
    *(short8_t*)(POh + o) = hi.v;
    *(short8_t*)(POl + o) = lo.v;
}

// ---------------------------------------------------------------------------
// trans_h0f: h0[b][k] -> A-fragment layout [copy][mt][ks][lane][8] bf16 hi/lo
// ---------------------------------------------------------------------------
__global__ __launch_bounds__(256) void trans_h0f(
    const float* __restrict__ h0, unsigned short* __restrict__ hA)
{
    int id = blockIdx.x * 256 + threadIdx.x;   // [0, 16384)
    int lane = id & 63;
    int ks = (id >> 6) & 31;
    int mt = (id >> 11) & 3;
    int copy = id >> 13;
    int b = mt * 16 + (lane & 15);
    int k = ks * 32 + (lane >> 4) * 8;
    const float* src = h0 + (size_t)b * 1024 + k;

    union { short8_t v; unsigned short u[8]; } o;
#pragma unroll
    for (int e = 0; e < 8; ++e) {
        float v = src[e];
        unsigned short hb = f2bf(v);
        o.u[e] = (copy == 0) ? hb : f2bf(v - bf2f(hb));
    }
    *(short8_t*)(hA + (size_t)id * 8) = o.v;
}

// ---------------------------------------------------------------------------
// xproj bf16 MFMA GEMM; epilogue scatters to xpf[t][ng(128)][b][jj(8)][g(4)].
// ---------------------------------------------------------------------------
__global__ __launch_bounds__(256) void xproj_mfma(
    const float* __restrict__ X,
    const float* __restrict__ W0, const float* __restrict__ W1,
    const float* __restrict__ W2, const float* __restrict__ W3,
    unsigned short* __restrict__ xpf)
{
    __shared__ short8_t As[4 * 128];
    __shared__ short8_t Bs[4 * 128];

    const int bm = blockIdx.x;
    const int bn = blockIdx.y;
    const float* W = (bn < 8) ? W0 : (bn < 16) ? W1 : (bn < 24) ? W2 : W3;
    const int jbase = (bn & 7) * 128;
    const int m0 = bm * 128;

    const int tid  = threadIdx.x;
    const int lane = tid & 63;
    const int wave = tid >> 6;
    const int wm = wave >> 1, wn = wave & 1;
    const int q  = lane >> 4;
    const int lr = lane & 15;

    f32x4 acc[4][4];
#pragma unroll
    for (int i = 0; i < 4; ++i)
#pragma unroll
        for (int j = 0; j < 4; ++j) acc[i][j] = (f32x4){0.f, 0.f, 0.f, 0.f};

    for (int k0 = 0; k0 < 1024; k0 += 32) {
#pragma unroll
        for (int ss = 0; ss < 2; ++ss) {
            int s  = tid + ss * 256;
            int kg = s & 3, r = s >> 2;
            const float* xa = X + (size_t)(m0 + r) * 1024 + k0 + kg * 8;
            const float* wb = W + (size_t)(jbase + r) * 1024 + k0 + kg * 8;
            float4 a0 = *(const float4*)(xa);
            float4 a1 = *(const float4*)(xa + 4);
            float4 b0 = *(const float4*)(wb);
            float4 b1 = *(const float4*)(wb + 4);
            union { short8_t v; unsigned short u[8]; } ua, ub;
            float af[8] = {a0.x,a0.y,a0.z,a0.w,a1.x,a1.y,a1.z,a1.w};
            float bf[8] = {b0.x,b0.y,b0.z,b0.w,b1.x,b1.y,b1.z,b1.w};
#pragma unroll
            for (int e = 0; e < 8; ++e) {
                ua.u[e] = f2bf(af[e]);
                ub.u[e] = f2bf(bf[e]);
            }
            As[kg * 128 + r] = ua.v;
            Bs[kg * 128 + r] = ub.v;
        }
        __syncthreads();

        short8_t a[4], b[4];
#pragma unroll
        for (int mi = 0; mi < 4; ++mi)
            a[mi] = As[q * 128 + wm * 64 + mi * 16 + lr];
#pragma unroll
        for (int nj = 0; nj < 4; ++nj)
            b[nj] = Bs[q * 128 + wn * 64 + nj * 16 + lr];
#pragma unroll
        for (int mi = 0; mi < 4; ++mi)
#pragma unroll
            for (int nj = 0; nj < 4; ++nj)
                acc[mi][nj] = __builtin_amdgcn_mfma_f32_16x16x32_bf16(
                    a[mi], b[nj], acc[mi][nj], 0, 0, 0);
        __syncthreads();
    }

#pragma unroll
    for (int mi = 0; mi < 4; ++mi)
#pragma unroll
        for (int nj = 0; nj < 4; ++nj)
#pragma unroll
            for (int r = 0; r < 4; ++r) {
                int m = m0 + wm * 64 + mi * 16 + q * 4 + r;
                int n = bn * 128 + wn * 64 + nj * 16 + lr;
                int tt = m >> 6, bb = m & 63;
                int g = n >> 10, jc = n & 1023;
                xpf[(((size_t)tt * NBLK + (jc >> 3)) * 64 + bb) * 32 + (jc & 7) * 4 + g]
                    = f2bf(acc[mi][nj][r]);
            }
}

// ---------------------------------------------------------------------------
// Persistent MFMA LSTM loop. Round-14: stripe-local barrier release.
// Wave kq reads h only for k in [128kq,128kq+128), written exactly by
// stripes 2kq and 2kq+1 (blocks 16kq..16kq+15). Arrival = 1 fetch_add on
// own stripe counter; release = each wave polls its TWO source stripes.
// Master counter + flag rebroadcast deleted (2 fewer serialized L3 hops).
// Block still joins all 16 stripes per step via its 8 waves + syncthreads,
// so the 2-slab ping-pong invariant is unchanged.
// ---------------------------------------------------------------------------
__global__ __launch_bounds__(512, 1) void lstm_loop12(
    const unsigned short* __restrict__ xpf,
    const unsigned short* __restrict__ PGh, const unsigned short* __restrict__ PGl,
    const unsigned short* __restrict__ POh, const unsigned short* __restrict__ POl,
    const float* __restrict__ c0,
    unsigned short* __restrict__ hA, unsigned short* __restrict__ hB,
    float* __restrict__ out,
    unsigned* __restrict__ bar)
{
    __shared__ f32x4 red[8][12][64];    // [wave][mt*3+nc][lane]  96 KB
    __shared__ f32x4 redF[12][64];      //                        12 KB

    const int tid  = threadIdx.x;
    const int lane = tid & 63;
    const int kq   = tid >> 6;
    const int ng   = blockIdx.x;        // 0..127

    // ---- persistent B fragments in registers ----
    short8_t bgh[2][4], bgl[2][4], boh[4], bol[4];
#pragma unroll
    for (int i = 0; i < 4; ++i) {
        int ks = 4 * kq + i;
#pragma unroll
        for (int nt = 0; nt < 2; ++nt) {
            size_t og = (((size_t)(ng * 2 + nt) * 32 + ks) * 64 + lane) * 8;
            bgh[nt][i] = *(const short8_t*)(PGh + og);
            bgl[nt][i] = *(const short8_t*)(PGl + og);
        }
        short8_t zh = {0,0,0,0,0,0,0,0};
        short8_t zl = {0,0,0,0,0,0,0,0};
        if ((lane & 15) < 8) {
            size_t oo = (((size_t)ng * 32 + ks) * 32 + (lane >> 4) * 8 + (lane & 7)) * 8;
            zh = *(const short8_t*)(POh + oo);
            zl = *(const short8_t*)(POl + oo);
        }
        boh[i] = zh; bol[i] = zl;
    }

    // combine identity: all 512 threads, b = tid>>3, jj = tid&7
    const int cb = tid >> 3, cjj = tid & 7;
    float c_reg = c0[(size_t)cb * 1024 + 8 * ng + cjj];
    ushort4_t xq = *(const ushort4_t*)(xpf + ((size_t)ng * 64 + cb) * 32 + cjj * 4);

    // h-store address pieces: j-range [8ng,8ng+8) = one full 8-elem k-group
    const int ks2  = ng >> 2;
    const int l2hi = (ng & 3) << 4;
    const unsigned hbase = ((((unsigned)(cb >> 4)) * 32 + ks2) * 64 + ((cb & 15) | l2hi)) * 8 + cjj;

    // stripe counters: arrival on own stripe; poll the 2 source stripes of kq
    unsigned* myStripe = bar + (ng >> 3) * 32;
    unsigned* src0 = bar + (2 * kq)     * 32;
    unsigned* src1 = bar + (2 * kq + 1) * 32;

#pragma unroll 1
    for (int t = 0; t <= T_STEPS; ++t) {
        const unsigned short* hc = (t & 1) ? hB : hA;
        unsigned short*       hn = (t & 1) ? hA : hB;

        // ---- hoisted h loads: all 4 k-groups x 4 m-tiles x hi/lo at once ----
        short8_t ah[4][4], al[4][4];
#pragma unroll
        for (int i = 0; i < 4; ++i) {
            const int ks = 4 * kq + i;
#pragma unroll
            for (int mt = 0; mt < 4; ++mt) {
                int off = ((mt * 32 + ks) * 64 + lane) * 8;
                union { short8_t v; unsigned long long q[2]; } uh, ul;
                const unsigned long long* ph = (const unsigned long long*)(hc + off);
                const unsigned long long* pl = (const unsigned long long*)(hc + 65536 + off);
                uh.q[0] = __hip_atomic_load(ph,     __ATOMIC_RELAXED, __HIP_MEMORY_SCOPE_SYSTEM);
                uh.q[1] = __hip_atomic_load(ph + 1, __ATOMIC_RELAXED, __HIP_MEMORY_SCOPE_SYSTEM);
                ul.q[0] = __hip_atomic_load(pl,     __ATOMIC_RELAXED, __HIP_MEMORY_SCOPE_SYSTEM);
                ul.q[1] = __hip_atomic_load(pl + 1, __ATOMIC_RELAXED, __HIP_MEMORY_SCOPE_SYSTEM);
                ah[i][mt] = uh.v;
                al[i][mt] = ul.v;
            }
        }

        f32x4 acc[4][3];
#pragma unroll
        for (int mt = 0; mt < 4; ++mt)
#pragma unroll
            for (int nc = 0; nc < 3; ++nc)
                acc[mt][nc] = (f32x4){0.f, 0.f, 0.f, 0.f};

#pragma unroll
        for (int i = 0; i < 4; ++i) {
#pragma unroll
            for (int mt = 0; mt < 4; ++mt) {
                acc[mt][0] = __builtin_amdgcn_mfma_f32_16x16x32_bf16(ah[i][mt], bgh[0][i], acc[mt][0], 0,0,0);
                acc[mt][1] = __builtin_amdgcn_mfma_f32_16x16x32_bf16(ah[i][mt], bgh[1][i], acc[mt][1], 0,0,0);
                acc[mt][2] = __builtin_amdgcn_mfma_f32_16x16x32_bf16(ah[i][mt], boh[i],    acc[mt][2], 0,0,0);
                acc[mt][0] = __builtin_amdgcn_mfma_f32_16x16x32_bf16(al[i][mt], bgh[0][i], acc[mt][0], 0,0,0);
                acc[mt][1] = __builtin_amdgcn_mfma_f32_16x16x32_bf16(al[i][mt], bgh[1][i], acc[mt][1], 0,0,0);
                acc[mt][2] = __builtin_amdgcn_mfma_f32_16x16x32_bf16(al[i][mt], boh[i],    acc[mt][2], 0,0,0);
                acc[mt][0] = __builtin_amdgcn_mfma_f32_16x16x32_bf16(ah[i][mt], bgl[0][i], acc[mt][0], 0,0,0);
                acc[mt][1] = __builtin_amdgcn_mfma_f32_16x16x32_bf16(ah[i][mt], bgl[1][i], acc[mt][1], 0,0,0);
                acc[mt][2] = __builtin_amdgcn_mfma_f32_16x16x32_bf16(ah[i][mt], bol[i],    acc[mt][2], 0,0,0);
            }
        }

        // ---- K-reduction across 8 waves (12 tiles) ----
#pragma unroll
        for (int mt = 0; mt < 4; ++mt)
#pragma unroll
            for (int nc = 0; nc < 3; ++nc)
                red[kq][mt * 3 + nc][lane] = acc[mt][nc];
        __syncthreads();
        {
            f32x4 s = red[0][kq][lane];
#pragma unroll
            for (int q = 1; q < 8; ++q) s += red[q][kq][lane];
            redF[kq][lane] = s;
        }
        if (kq < 4) {
            const int tl = 8 + kq;
            f32x4 s = red[0][tl][lane];
#pragma unroll
            for (int q = 1; q < 8; ++q) s += red[q][tl][lane];
            redF[tl][lane] = s;
        }
        __syncthreads();

        // ---- combine (all 512 threads): gates -> c,h (direct publish) ----
        float ov;
        {
            const int mt = cb >> 4;
            const int lnb = (cb & 12) << 2;
            const int rg = cb & 3;
            ov = redF[mt * 3 + 2][lnb | cjj][rg];
            if (t < T_STEPS) {
                const int nt = cjj >> 2;
                float pre0 = redF[mt * 3 + nt][lnb | (0  + (cjj & 3))][rg] + bf2f(xq[0]);
                float pre1 = redF[mt * 3 + nt][lnb | (4  + (cjj & 3))][rg] + bf2f(xq[1]);
                float pre2 = redF[mt * 3 + nt][lnb | (8  + (cjj & 3))][rg] + bf2f(xq[2]);
                float pre3 = redF[mt * 3 + nt][lnb | (12 + (cjj & 3))][rg] + bf2f(xq[3]);
                float gi = 1.f / (1.f + expf(-pre0));
                float gf = 1.f / (1.f + expf(-pre1));
                float go = 1.f / (1.f + expf(-pre2));
                float cn = gf * c_reg + gi * tanhf(pre3);
                c_reg = cn;
                float hv = go * tanhf(cn);
                unsigned short hhi = f2bf(hv);
                unsigned short hlo = f2bf(hv - bf2f(hhi));

                // pair-pack with neighbor lane (cjj+1) and publish directly
                unsigned hhiN = (unsigned short)__shfl_down((int)hhi, 1);
                unsigned hloN = (unsigned short)__shfl_down((int)hlo, 1);
                if ((cjj & 1) == 0) {
                    unsigned hp = (unsigned)hhi | (hhiN << 16);
                    unsigned lp = (unsigned)hlo | (hloN << 16);
                    __hip_atomic_store((unsigned*)(hn + hbase), hp,
                                       __ATOMIC_RELAXED, __HIP_MEMORY_SCOPE_SYSTEM);
                    __hip_atomic_store((unsigned*)(hn + hbase + 65536), lp,
                                       __ATOMIC_RELAXED, __HIP_MEMORY_SCOPE_SYSTEM);
                }
                if (t + 1 < T_STEPS)
                    xq = *(const ushort4_t*)(xpf +
                        (((size_t)(t + 1) * NBLK + ng) * 64 + cb) * 32 + cjj * 4);
            }
        }

        // ---- stripe-local barrier: arrive own stripe; poll 2 source stripes ----
        if (t < T_STEPS) {
            __syncthreads();   // all waves' h stores drained before arrival
            const unsigned tgt = 8u * (unsigned)(t + 1);
            if (tid == 0)
                __hip_atomic_fetch_add(myStripe, 1u,
                                       __ATOMIC_RELAXED, __HIP_MEMORY_SCOPE_SYSTEM);
            while (__hip_atomic_load(src0, __ATOMIC_RELAXED, __HIP_MEMORY_SCOPE_SYSTEM) < tgt)
                __builtin_amdgcn_s_sleep(1);
            while (__hip_atomic_load(src1, __ATOMIC_RELAXED, __HIP_MEMORY_SCOPE_SYSTEM) < tgt)
                __builtin_amdgcn_s_sleep(1);
        }

        // ---- out[t-1] write (post-barrier: out of the drain path) ----
        if (t > 0)
            out[(size_t)(t - 1) * 65536 + cb * 1024 + 8 * ng + cjj] = ov;
    }
}

// ---------------------------------------------------------------------------
extern "C" void kernel_launch(void* const* d_in, const int* in_sizes, int n_in,
                              void* d_out, int out_size, void* d_ws, size_t ws_size,
                              hipStream_t stream)
{
    const float* x    = (const float*)d_in[0];
    const float* h0   = (const float*)d_in[1];
    const float* c0   = (const float*)d_in[2];
    const float* Wxi  = (const float*)d_in[3];
    const float* Wxf  = (const float*)d_in[4];
    const float* Wxo  = (const float*)d_in[5];
    const float* Wxc  = (const float*)d_in[6];
    const float* Whi  = (const float*)d_in[7];
    const float* Whf  = (const float*)d_in[8];
    const float* Who  = (const float*)d_in[9];
    const float* Whc  = (const float*)d_in[10];
    const float* Wout = (const float*)d_in[11];
    float* out = (float*)d_out;

    const size_t PG_B  = (size_t)NBLK * 2 * 32 * 64 * 8 * 2;   //  8,388,608 each
    const size_t PO_B  = (size_t)NBLK * 32 * 32 * 8 * 2;       //  2,097,152 each
    const size_t HF_B  = (size_t)2 * 4 * 32 * 64 * 8 * 2;      //    262,144 each
    const size_t BAR_B = 8192;
    const size_t XPF_B = (size_t)T_STEPS * NBLK * 64 * 32 * 2; // 134,217,728

    char* ws = (char*)d_ws;
    unsigned short* PGh = (unsigned short*)ws;  ws += PG_B;
    unsigned short* PGl = (unsigned short*)ws;  ws += PG_B;
    unsigned short* POh = (unsigned short*)ws;  ws += PO_B;
    unsigned short* POl = (unsigned short*)ws;  ws += PO_B;
    unsigned short* hA  = (unsigned short*)ws;  ws += HF_B;
    unsigned short* hB  = (unsigned short*)ws;  ws += HF_B;
    unsigned*       bar = (unsigned*)ws;        ws += BAR_B;
    unsigned short* xpf = (unsigned short*)ws;  ws += XPF_B;

    hipMemsetAsync(bar, 0, BAR_B, stream);
    pack_gate<<<dim3(16, NBLK), 256, 0, stream>>>(Whi, Whf, Who, Whc, PGh, PGl);
    pack_out<<<dim3(4, NBLK), 256, 0, stream>>>(Wout, POh, POl);
    trans_h0f<<<dim3(64), 256, 0, stream>>>(h0, hA);
    xproj_mfma<<<dim3(128, 32), 256, 0, stream>>>(x, Wxi, Wxf, Wxo, Wxc, xpf);

    lstm_loop12<<<dim3(NBLK), dim3(512), 0, stream>>>(
        xpf, PGh, PGl, POh, POl, c0, hA, hB, out, bar);
}

// Round 15
// 2595.799 us; speedup vs baseline: 1.0293x; 1.0293x over previous
//
#include <hip/hip_runtime.h>
#include <hip/hip_bf16.h>
#include <math.h>

#define T_STEPS 256
#define NBLK    128

typedef __attribute__((ext_vector_type(8))) short short8_t;   // 8 bf16
typedef __attribute__((ext_vector_type(4))) float f32x4;
typedef __attribute__((ext_vector_type(4))) unsigned short ushort4_t;

__device__ __forceinline__ unsigned short f2bf(float v) {
    __hip_bfloat16 h = __float2bfloat16(v);
    return *reinterpret_cast<unsigned short*>(&h);
}
__device__ __forceinline__ float bf2f(unsigned short u) {
    __hip_bfloat16 h;
    *reinterpret_cast<unsigned short*>(&h) = u;
    return __bfloat162float(h);
}

// ---------------------------------------------------------------------------
// pack_gate: gate-weight B-fragments for 128-block layout, bf16 hi/lo.
// ---------------------------------------------------------------------------
__global__ __launch_bounds__(256) void pack_gate(
    const float* __restrict__ Wi, const float* __restrict__ Wf,
    const float* __restrict__ Wo, const float* __restrict__ Wc,
    unsigned short* __restrict__ PGh, unsigned short* __restrict__ PGl)
{
    int ng = blockIdx.y;
    int slot = blockIdx.x * 4 + (threadIdx.x >> 6);   // 0..63
    int nt = slot >> 5, ks = slot & 31;
    int lane = threadIdx.x & 63;
    int n = lane & 15, g = n >> 2;
    int j = 8 * ng + nt * 4 + (n & 3);
    int k0 = ks * 32 + (lane >> 4) * 8;
    const float* W = (g == 0) ? Wi : (g == 1) ? Wf : (g == 2) ? Wo : Wc;
    const float* src = W + (size_t)j * 1024 + k0;

    union { short8_t v; unsigned short u[8]; } hi, lo;
#pragma unroll
    for (int e = 0; e < 8; ++e) {
        float v = src[e];
        hi.u[e] = f2bf(v);
        lo.u[e] = f2bf(v - bf2f(hi.u[e]));
    }
    size_t o = (((size_t)(ng * 2 + nt) * 32 + ks) * 64 + lane) * 8;
    *(short8_t*)(PGh + o) = hi.v;
    *(short8_t*)(PGl + o) = lo.v;
}

// ---------------------------------------------------------------------------
// pack_out: compact out-weight frags (8 real cols per block).
// ---------------------------------------------------------------------------
__global__ __launch_bounds__(256) void pack_out(
    const float* __restrict__ Wout,
    unsigned short* __restrict__ POh, unsigned short* __restrict__ POl)
{
    int ng = blockIdx.y;
    int ks = blockIdx.x * 8 + (threadIdx.x >> 5);
    int sl = threadIdx.x & 31;
    int kb = sl >> 3, n = sl & 7;
    int j = 8 * ng + n;
    int k0 = ks * 32 + kb * 8;
    const float* src = Wout + (size_t)j * 1024 + k0;

    union { short8_t v; unsigned short u[8]; } hi, lo;
#pragma unroll
    for (int e = 0; e < 8; ++e) {
        float v = src[e];
        hi.u[e] = f2bf(v);
        lo.u[e] = f2bf(v - bf2f(hi.u[e]));
    }
    size_t o = (((size_t)ng * 32 + ks) * 32 + sl) * 8;
    *(short8_t*)(POh + o) = hi.v;
    *(short8_t*)(POl + o) = lo.v;
}

// ---------------------------------------------------------------------------
// trans_h0f: h0[b][k] -> A-fragment layout [copy][mt][ks][lane][8] bf16 hi/lo
// ---------------------------------------------------------------------------
__global__ __launch_bounds__(256) void trans_h0f(
    const float* __restrict__ h0, unsigned short* __restrict__ hA)
{
    int id = blockIdx.x * 256 + threadIdx.x;   // [0, 16384)
    int lane = id & 63;
    int ks = (id >> 6) & 31;
    int mt = (id >> 11) & 3;
    int copy = id >> 13;
    int b = mt * 16 + (lane & 15);
    int k = ks * 32 + (lane >> 4) * 8;
    const float* src = h0 + (size_t)b * 1024 + k;

    union { short8_t v; unsigned short u[8]; } o;
#pragma unroll
    for (int e = 0; e < 8; ++e) {
        float v = src[e];
        unsigned short hb = f2bf(v);
        o.u[e] = (copy == 0) ? hb : f2bf(v - bf2f(hb));
    }
    *(short8_t*)(hA + (size_t)id * 8) = o.v;
}

// ---------------------------------------------------------------------------
// xproj bf16 MFMA GEMM; epilogue scatters to xpf[t][ng(128)][b][jj(8)][g(4)].
// ---------------------------------------------------------------------------
__global__ __launch_bounds__(256) void xproj_mfma(
    const float* __restrict__ X,
    const float* __restrict__ W0, const float* __restrict__ W1,
    const float* __restrict__ W2, const float* __restrict__ W3,
    unsigned short* __restrict__ xpf)
{
    __shared__ short8_t As[4 * 128];
    __shared__ short8_t Bs[4 * 128];

    const int bm = blockIdx.x;
    const int bn = blockIdx.y;
    const float* W = (bn < 8) ? W0 : (bn < 16) ? W1 : (bn < 24) ? W2 : W3;
    const int jbase = (bn & 7) * 128;
    const int m0 = bm * 128;

    const int tid  = threadIdx.x;
    const int lane = tid & 63;
    const int wave = tid >> 6;
    const int wm = wave >> 1, wn = wave & 1;
    const int q  = lane >> 4;
    const int lr = lane & 15;

    f32x4 acc[4][4];
#pragma unroll
    for (int i = 0; i < 4; ++i)
#pragma unroll
        for (int j = 0; j < 4; ++j) acc[i][j] = (f32x4){0.f, 0.f, 0.f, 0.f};

    for (int k0 = 0; k0 < 1024; k0 += 32) {
#pragma unroll
        for (int ss = 0; ss < 2; ++ss) {
            int s  = tid + ss * 256;
            int kg = s & 3, r = s >> 2;
            const float* xa = X + (size_t)(m0 + r) * 1024 + k0 + kg * 8;
            const float* wb = W + (size_t)(jbase + r) * 1024 + k0 + kg * 8;
            float4 a0 = *(const float4*)(xa);
            float4 a1 = *(const float4*)(xa + 4);
            float4 b0 = *(const float4*)(wb);
            float4 b1 = *(const float4*)(wb + 4);
            union { short8_t v; unsigned short u[8]; } ua, ub;
            float af[8] = {a0.x,a0.y,a0.z,a0.w,a1.x,a1.y,a1.z,a1.w};
            float bf[8] = {b0.x,b0.y,b0.z,b0.w,b1.x,b1.y,b1.z,b1.w};
#pragma unroll
            for (int e = 0; e < 8; ++e) {
                ua.u[e] = f2bf(af[e]);
                ub.u[e] = f2bf(bf[e]);
            }
            As[kg * 128 + r] = ua.v;
            Bs[kg * 128 + r] = ub.v;
        }
        __syncthreads();

        short8_t a[4], b[4];
#pragma unroll
        for (int mi = 0; mi < 4; ++mi)
            a[mi] = As[q * 128 + wm * 64 + mi * 16 + lr];
#pragma unroll
        for (int nj = 0; nj < 4; ++nj)
            b[nj] = Bs[q * 128 + wn * 64 + nj * 16 + lr];
#pragma unroll
        for (int mi = 0; mi < 4; ++mi)
#pragma unroll
            for (int nj = 0; nj < 4; ++nj)
                acc[mi][nj] = __builtin_amdgcn_mfma_f32_16x16x32_bf16(
                    a[mi], b[nj], acc[mi][nj], 0, 0, 0);
        __syncthreads();
    }

#pragma unroll
    for (int mi = 0; mi < 4; ++mi)
#pragma unroll
        for (int nj = 0; nj < 4; ++nj)
#pragma unroll
            for (int r = 0; r < 4; ++r) {
                int m = m0 + wm * 64 + mi * 16 + q * 4 + r;
                int n = bn * 128 + wn * 64 + nj * 16 + lr;
                int tt = m >> 6, bb = m & 63;
                int g = n >> 10, jc = n & 1023;
                xpf[(((size_t)tt * NBLK + (jc >> 3)) * 64 + bb) * 32 + (jc & 7) * 4 + g]
                    = f2bf(acc[mi][nj][r]);
            }
}

// ---------------------------------------------------------------------------
// Persistent MFMA LSTM loop. Round-15 = round-13 structure (proven best:
// hoisted h loads, per-wave flag polling, striped barrier with store-only
// flag lines) + ONE change: xq prefetch moved AFTER the barrier poll so its
// cold-HBM latency is not part of the pre-arrival vmcnt(0) drain.
// ---------------------------------------------------------------------------
__global__ __launch_bounds__(512, 1) void lstm_loop13(
    const unsigned short* __restrict__ xpf,
    const unsigned short* __restrict__ PGh, const unsigned short* __restrict__ PGl,
    const unsigned short* __restrict__ POh, const unsigned short* __restrict__ POl,
    const float* __restrict__ c0,
    unsigned short* __restrict__ hA, unsigned short* __restrict__ hB,
    float* __restrict__ out,
    unsigned* __restrict__ bar)
{
    __shared__ f32x4 red[8][12][64];    // [wave][mt*3+nc][lane]  96 KB
    __shared__ f32x4 redF[12][64];      //                        12 KB

    const int tid  = threadIdx.x;
    const int lane = tid & 63;
    const int kq   = tid >> 6;
    const int ng   = blockIdx.x;        // 0..127

    // ---- persistent B fragments in registers ----
    short8_t bgh[2][4], bgl[2][4], boh[4], bol[4];
#pragma unroll
    for (int i = 0; i < 4; ++i) {
        int ks = 4 * kq + i;
#pragma unroll
        for (int nt = 0; nt < 2; ++nt) {
            size_t og = (((size_t)(ng * 2 + nt) * 32 + ks) * 64 + lane) * 8;
            bgh[nt][i] = *(const short8_t*)(PGh + og);
            bgl[nt][i] = *(const short8_t*)(PGl + og);
        }
        short8_t zh = {0,0,0,0,0,0,0,0};
        short8_t zl = {0,0,0,0,0,0,0,0};
        if ((lane & 15) < 8) {
            size_t oo = (((size_t)ng * 32 + ks) * 32 + (lane >> 4) * 8 + (lane & 7)) * 8;
            zh = *(const short8_t*)(POh + oo);
            zl = *(const short8_t*)(POl + oo);
        }
        boh[i] = zh; bol[i] = zl;
    }

    // combine identity: all 512 threads, b = tid>>3, jj = tid&7
    const int cb = tid >> 3, cjj = tid & 7;
    float c_reg = c0[(size_t)cb * 1024 + 8 * ng + cjj];
    ushort4_t xq = *(const ushort4_t*)(xpf + ((size_t)ng * 64 + cb) * 32 + cjj * 4);

    // h-store address pieces: j-range [8ng,8ng+8) = one full 8-elem k-group
    const int ks2  = ng >> 2;
    const int l2hi = (ng & 3) << 4;
    const unsigned hbase = ((((unsigned)(cb >> 4)) * 32 + ks2) * 64 + ((cb & 15) | l2hi)) * 8 + cjj;

    // flag replica this block polls
    unsigned* flagp = bar + 576 + (ng & 15) * 32;

#pragma unroll 1
    for (int t = 0; t <= T_STEPS; ++t) {
        const unsigned short* hc = (t & 1) ? hB : hA;
        unsigned short*       hn = (t & 1) ? hA : hB;

        // ---- hoisted h loads: all 4 k-groups x 4 m-tiles x hi/lo at once ----
        short8_t ah[4][4], al[4][4];
#pragma unroll
        for (int i = 0; i < 4; ++i) {
            const int ks = 4 * kq + i;
#pragma unroll
            for (int mt = 0; mt < 4; ++mt) {
                int off = ((mt * 32 + ks) * 64 + lane) * 8;
                union { short8_t v; unsigned long long q[2]; } uh, ul;
                const unsigned long long* ph = (const unsigned long long*)(hc + off);
                const unsigned long long* pl = (const unsigned long long*)(hc + 65536 + off);
                uh.q[0] = __hip_atomic_load(ph,     __ATOMIC_RELAXED, __HIP_MEMORY_SCOPE_SYSTEM);
                uh.q[1] = __hip_atomic_load(ph + 1, __ATOMIC_RELAXED, __HIP_MEMORY_SCOPE_SYSTEM);
                ul.q[0] = __hip_atomic_load(pl,     __ATOMIC_RELAXED, __HIP_MEMORY_SCOPE_SYSTEM);
                ul.q[1] = __hip_atomic_load(pl + 1, __ATOMIC_RELAXED, __HIP_MEMORY_SCOPE_SYSTEM);
                ah[i][mt] = uh.v;
                al[i][mt] = ul.v;
            }
        }

        f32x4 acc[4][3];
#pragma unroll
        for (int mt = 0; mt < 4; ++mt)
#pragma unroll
            for (int nc = 0; nc < 3; ++nc)
                acc[mt][nc] = (f32x4){0.f, 0.f, 0.f, 0.f};

#pragma unroll
        for (int i = 0; i < 4; ++i) {
#pragma unroll
            for (int mt = 0; mt < 4; ++mt) {
                acc[mt][0] = __builtin_amdgcn_mfma_f32_16x16x32_bf16(ah[i][mt], bgh[0][i], acc[mt][0], 0,0,0);
                acc[mt][1] = __builtin_amdgcn_mfma_f32_16x16x32_bf16(ah[i][mt], bgh[1][i], acc[mt][1], 0,0,0);
                acc[mt][2] = __builtin_amdgcn_mfma_f32_16x16x32_bf16(ah[i][mt], boh[i],    acc[mt][2], 0,0,0);
                acc[mt][0] = __builtin_amdgcn_mfma_f32_16x16x32_bf16(al[i][mt], bgh[0][i], acc[mt][0], 0,0,0);
                acc[mt][1] = __builtin_amdgcn_mfma_f32_16x16x32_bf16(al[i][mt], bgh[1][i], acc[mt][1], 0,0,0);
                acc[mt][2] = __builtin_amdgcn_mfma_f32_16x16x32_bf16(al[i][mt], boh[i],    acc[mt][2], 0,0,0);
                acc[mt][0] = __builtin_amdgcn_mfma_f32_16x16x32_bf16(ah[i][mt], bgl[0][i], acc[mt][0], 0,0,0);
                acc[mt][1] = __builtin_amdgcn_mfma_f32_16x16x32_bf16(ah[i][mt], bgl[1][i], acc[mt][1], 0,0,0);
                acc[mt][2] = __builtin_amdgcn_mfma_f32_16x16x32_bf16(ah[i][mt], bol[i],    acc[mt][2], 0,0,0);
            }
        }

        // ---- K-reduction across 8 waves (12 tiles) ----
#pragma unroll
        for (int mt = 0; mt < 4; ++mt)
#pragma unroll
            for (int nc = 0; nc < 3; ++nc)
                red[kq][mt * 3 + nc][lane] = acc[mt][nc];
        __syncthreads();
        {
            f32x4 s = red[0][kq][lane];
#pragma unroll
            for (int q = 1; q < 8; ++q) s += red[q][kq][lane];
            redF[kq][lane] = s;
        }
        if (kq < 4) {
            const int tl = 8 + kq;
            f32x4 s = red[0][tl][lane];
#pragma unroll
            for (int q = 1; q < 8; ++q) s += red[q][tl][lane];
            redF[tl][lane] = s;
        }
        __syncthreads();

        // ---- combine (all 512 threads): gates -> c,h (direct publish) ----
        float ov;
        {
            const int mt = cb >> 4;
            const int lnb = (cb & 12) << 2;
            const int rg = cb & 3;
            ov = redF[mt * 3 + 2][lnb | cjj][rg];
            if (t < T_STEPS) {
                const int nt = cjj >> 2;
                float pre0 = redF[mt * 3 + nt][lnb | (0  + (cjj & 3))][rg] + bf2f(xq[0]);
                float pre1 = redF[mt * 3 + nt][lnb | (4  + (cjj & 3))][rg] + bf2f(xq[1]);
                float pre2 = redF[mt * 3 + nt][lnb | (8  + (cjj & 3))][rg] + bf2f(xq[2]);
                float pre3 = redF[mt * 3 + nt][lnb | (12 + (cjj & 3))][rg] + bf2f(xq[3]);
                float gi = 1.f / (1.f + expf(-pre0));
                float gf = 1.f / (1.f + expf(-pre1));
                float go = 1.f / (1.f + expf(-pre2));
                float cn = gf * c_reg + gi * tanhf(pre3);
                c_reg = cn;
                float hv = go * tanhf(cn);
                unsigned short hhi = f2bf(hv);
                unsigned short hlo = f2bf(hv - bf2f(hhi));

                // pair-pack with neighbor lane (cjj+1) and publish directly
                unsigned hhiN = (unsigned short)__shfl_down((int)hhi, 1);
                unsigned hloN = (unsigned short)__shfl_down((int)hlo, 1);
                if ((cjj & 1) == 0) {
                    unsigned hp = (unsigned)hhi | (hhiN << 16);
                    unsigned lp = (unsigned)hlo | (hloN << 16);
                    __hip_atomic_store((unsigned*)(hn + hbase), hp,
                                       __ATOMIC_RELAXED, __HIP_MEMORY_SCOPE_SYSTEM);
                    __hip_atomic_store((unsigned*)(hn + hbase + 65536), lp,
                                       __ATOMIC_RELAXED, __HIP_MEMORY_SCOPE_SYSTEM);
                }
            }
        }

        // ---- striped grid barrier: relaxed SYSTEM; per-wave flag polling ----
        if (t < T_STEPS) {
            __syncthreads();   // all waves' h stores drained before arrival
            const unsigned tgt = (unsigned)(t + 1);
            if (tid == 0) {
                unsigned* scnt = bar + (ng >> 3) * 32;            // 16 stripes
                unsigned old = __hip_atomic_fetch_add(scnt, 1u,
                                   __ATOMIC_RELAXED, __HIP_MEMORY_SCOPE_SYSTEM);
                if (old == 8u * tgt - 1u) {
                    unsigned om = __hip_atomic_fetch_add(bar + 512, 1u,
                                   __ATOMIC_RELAXED, __HIP_MEMORY_SCOPE_SYSTEM);
                    if (om == 16u * tgt - 1u) {
#pragma unroll
                        for (int f = 0; f < 16; ++f)
                            __hip_atomic_store(bar + 576 + f * 32, tgt,
                                   __ATOMIC_RELAXED, __HIP_MEMORY_SCOPE_SYSTEM);
                    }
                }
            }
            // every wave polls its replica; releases itself the moment it flips
            while (__hip_atomic_load(flagp, __ATOMIC_RELAXED, __HIP_MEMORY_SCOPE_SYSTEM) < tgt)
                __builtin_amdgcn_s_sleep(1);
        }

        // ---- post-barrier: xq prefetch for t+1 (latency hides under next
        //      step's h loads + MFMA) and out[t-1] write ----
        if (t + 1 < T_STEPS)
            xq = *(const ushort4_t*)(xpf +
                (((size_t)(t + 1) * NBLK + ng) * 64 + cb) * 32 + cjj * 4);
        if (t > 0)
            out[(size_t)(t - 1) * 65536 + cb * 1024 + 8 * ng + cjj] = ov;
    }
}

// ---------------------------------------------------------------------------
extern "C" void kernel_launch(void* const* d_in, const int* in_sizes, int n_in,
                              void* d_out, int out_size, void* d_ws, size_t ws_size,
                              hipStream_t stream)
{
    const float* x    = (const float*)d_in[0];
    const float* h0   = (const float*)d_in[1];
    const float* c0   = (const float*)d_in[2];
    const float* Wxi  = (const float*)d_in[3];
    const float* Wxf  = (const float*)d_in[4];
    const float* Wxo  = (const float*)d_in[5];
    const float* Wxc  = (const float*)d_in[6];
    const float* Whi  = (const float*)d_in[7];
    const float* Whf  = (const float*)d_in[8];
    const float* Who  = (const float*)d_in[9];
    const float* Whc  = (const float*)d_in[10];
    const float* Wout = (const float*)d_in[11];
    float* out = (float*)d_out;

    const size_t PG_B  = (size_t)NBLK * 2 * 32 * 64 * 8 * 2;   //  8,388,608 each
    const size_t PO_B  = (size_t)NBLK * 32 * 32 * 8 * 2;       //  2,097,152 each
    const size_t HF_B  = (size_t)2 * 4 * 32 * 64 * 8 * 2;      //    262,144 each
    const size_t BAR_B = 8192;
    const size_t XPF_B = (size_t)T_STEPS * NBLK * 64 * 32 * 2; // 134,217,728

    char* ws = (char*)d_ws;
    unsigned short* PGh = (unsigned short*)ws;  ws += PG_B;
    unsigned short* PGl = (unsigned short*)ws;  ws += PG_B;
    unsigned short* POh = (unsigned short*)ws;  ws += PO_B;
    unsigned short* POl = (unsigned short*)ws;  ws += PO_B;
    unsigned short* hA  = (unsigned short*)ws;  ws += HF_B;
    unsigned short* hB  = (unsigned short*)ws;  ws += HF_B;
    unsigned*       bar = (unsigned*)ws;        ws += BAR_B;
    unsigned short* xpf = (unsigned short*)ws;  ws += XPF_B;

    hipMemsetAsync(bar, 0, BAR_B, stream);
    pack_gate<<<dim3(16, NBLK), 256, 0, stream>>>(Whi, Whf, Who, Whc, PGh, PGl);
    pack_out<<<dim3(4, NBLK), 256, 0, stream>>>(Wout, POh, POl);
    trans_h0f<<<dim3(64), 256, 0, stream>>>(h0, hA);
    xproj_mfma<<<dim3(128, 32), 256, 0, stream>>>(x, Wxi, Wxf, Wxo, Wxc, xpf);

    lstm_loop13<<<dim3(NBLK), dim3(512), 0, stream>>>(
        xpf, PGh, PGl, POh, POl, c0, hA, hB, out, bar);
}

// Round 16
// 2560.377 us; speedup vs baseline: 1.0435x; 1.0138x over previous
//
#include <hip/hip_runtime.h>
#include <hip/hip_bf16.h>
#include <math.h>

#define T_STEPS 256
#define NBLK    128

typedef __attribute__((ext_vector_type(8))) short short8_t;   // 8 bf16
typedef __attribute__((ext_vector_type(4))) float f32x4;
typedef __attribute__((ext_vector_type(4))) unsigned short ushort4_t;

__device__ __forceinline__ unsigned short f2bf(float v) {
    __hip_bfloat16 h = __float2bfloat16(v);
    return *reinterpret_cast<unsigned short*>(&h);
}
__device__ __forceinline__ float bf2f(unsigned short u) {
    __hip_bfloat16 h;
    *reinterpret_cast<unsigned short*>(&h) = u;
    return __bfloat162float(h);
}

// ---------------------------------------------------------------------------
// pack_gate: gate-weight B-fragments for 128-block layout, bf16 hi/lo.
// ---------------------------------------------------------------------------
__global__ __launch_bounds__(256) void pack_gate(
    const float* __restrict__ Wi, const float* __restrict__ Wf,
    const float* __restrict__ Wo, const float* __restrict__ Wc,
    unsigned short* __restrict__ PGh, unsigned short* __restrict__ PGl)
{
    int ng = blockIdx.y;
    int slot = blockIdx.x * 4 + (threadIdx.x >> 6);   // 0..63
    int nt = slot >> 5, ks = slot & 31;
    int lane = threadIdx.x & 63;
    int n = lane & 15, g = n >> 2;
    int j = 8 * ng + nt * 4 + (n & 3);
    int k0 = ks * 32 + (lane >> 4) * 8;
    const float* W = (g == 0) ? Wi : (g == 1) ? Wf : (g == 2) ? Wo : Wc;
    const float* src = W + (size_t)j * 1024 + k0;

    union { short8_t v; unsigned short u[8]; } hi, lo;
#pragma unroll
    for (int e = 0; e < 8; ++e) {
        float v = src[e];
        hi.u[e] = f2bf(v);
        lo.u[e] = f2bf(v - bf2f(hi.u[e]));
    }
    size_t o = (((size_t)(ng * 2 + nt) * 32 + ks) * 64 + lane) * 8;
    *(short8_t*)(PGh + o) = hi.v;
    *(short8_t*)(PGl + o) = lo.v;
}

// ---------------------------------------------------------------------------
// pack_out: compact out-weight frags (8 real cols per block).
// ---------------------------------------------------------------------------
__global__ __launch_bounds__(256) void pack_out(
    const float* __restrict__ Wout,
    unsigned short* __restrict__ POh, unsigned short* __restrict__ POl)
{
    int ng = blockIdx.y;
    int ks = blockIdx.x * 8 + (threadIdx.x >> 5);
    int sl = threadIdx.x & 31;
    int kb = sl >> 3, n = sl & 7;
    int j = 8 * ng + n;
    int k0 = ks * 32 + kb * 8;
    const float* src = Wout + (size_t)j * 1024 + k0;

    union { short8_t v; unsigned short u[8]; } hi, lo;
#pragma unroll
    for (int e = 0; e < 8; ++e) {
        float v = src[e];
        hi.u[e] = f2bf(v);
        lo.u[e] = f2bf(v - bf2f(hi.u[e]));
    }
    size_t o = (((size_t)ng * 32 + ks) * 32 + sl) * 8;
    *(short8_t*)(POh + o) = hi.v;
    *(short8_t*)(POl + o) = lo.v;
}

// ---------------------------------------------------------------------------
// trans_h0f: h0[b][k] -> A-fragment layout [copy][mt][ks][lane][8] bf16 hi/lo
// ---------------------------------------------------------------------------
__global__ __launch_bounds__(256) void trans_h0f(
    const float* __restrict__ h0, unsigned short* __restrict__ hA)
{
    int id = blockIdx.x * 256 + threadIdx.x;   // [0, 16384)
    int lane = id & 63;
    int ks = (id >> 6) & 31;
    int mt = (id >> 11) & 3;
    int copy = id >> 13;
    int b = mt * 16 + (lane & 15);
    int k = ks * 32 + (lane >> 4) * 8;
    const float* src = h0 + (size_t)b * 1024 + k;

    union { short8_t v; unsigned short u[8]; } o;
#pragma unroll
    for (int e = 0; e < 8; ++e) {
        float v = src[e];
        unsigned short hb = f2bf(v);
        o.u[e] = (copy == 0) ? hb : f2bf(v - bf2f(hb));
    }
    *(short8_t*)(hA + (size_t)id * 8) = o.v;
}

// ---------------------------------------------------------------------------
// xproj bf16 MFMA GEMM; epilogue scatters to xpf[t][ng(128)][b][jj(8)][g(4)].
// ---------------------------------------------------------------------------
__global__ __launch_bounds__(256) void xproj_mfma(
    const float* __restrict__ X,
    const float* __restrict__ W0, const float* __restrict__ W1,
    const float* __restrict__ W2, const float* __restrict__ W3,
    unsigned short* __restrict__ xpf)
{
    __shared__ short8_t As[4 * 128];
    __shared__ short8_t Bs[4 * 128];

    const int bm = blockIdx.x;
    const int bn = blockIdx.y;
    const float* W = (bn < 8) ? W0 : (bn < 16) ? W1 : (bn < 24) ? W2 : W3;
    const int jbase = (bn & 7) * 128;
    const int m0 = bm * 128;

    const int tid  = threadIdx.x;
    const int lane = tid & 63;
    const int wave = tid >> 6;
    const int wm = wave >> 1, wn = wave & 1;
    const int q  = lane >> 4;
    const int lr = lane & 15;

    f32x4 acc[4][4];
#pragma unroll
    for (int i = 0; i < 4; ++i)
#pragma unroll
        for (int j = 0; j < 4; ++j) acc[i][j] = (f32x4){0.f, 0.f, 0.f, 0.f};

    for (int k0 = 0; k0 < 1024; k0 += 32) {
#pragma unroll
        for (int ss = 0; ss < 2; ++ss) {
            int s  = tid + ss * 256;
            int kg = s & 3, r = s >> 2;
            const float* xa = X + (size_t)(m0 + r) * 1024 + k0 + kg * 8;
            const float* wb = W + (size_t)(jbase + r) * 1024 + k0 + kg * 8;
            float4 a0 = *(const float4*)(xa);
            float4 a1 = *(const float4*)(xa + 4);
            float4 b0 = *(const float4*)(wb);
            float4 b1 = *(const float4*)(wb + 4);
            union { short8_t v; unsigned short u[8]; } ua, ub;
            float af[8] = {a0.x,a0.y,a0.z,a0.w,a1.x,a1.y,a1.z,a1.w};
            float bf[8] = {b0.x,b0.y,b0.z,b0.w,b1.x,b1.y,b1.z,b1.w};
#pragma unroll
            for (int e = 0; e < 8; ++e) {
                ua.u[e] = f2bf(af[e]);
                ub.u[e] = f2bf(bf[e]);
            }
            As[kg * 128 + r] = ua.v;
            Bs[kg * 128 + r] = ub.v;
        }
        __syncthreads();

        short8_t a[4], b[4];
#pragma unroll
        for (int mi = 0; mi < 4; ++mi)
            a[mi] = As[q * 128 + wm * 64 + mi * 16 + lr];
#pragma unroll
        for (int nj = 0; nj < 4; ++nj)
            b[nj] = Bs[q * 128 + wn * 64 + nj * 16 + lr];
#pragma unroll
        for (int mi = 0; mi < 4; ++mi)
#pragma unroll
            for (int nj = 0; nj < 4; ++nj)
                acc[mi][nj] = __builtin_amdgcn_mfma_f32_16x16x32_bf16(
                    a[mi], b[nj], acc[mi][nj], 0, 0, 0);
        __syncthreads();
    }

#pragma unroll
    for (int mi = 0; mi < 4; ++mi)
#pragma unroll
        for (int nj = 0; nj < 4; ++nj)
#pragma unroll
            for (int r = 0; r < 4; ++r) {
                int m = m0 + wm * 64 + mi * 16 + q * 4 + r;
                int n = bn * 128 + wn * 64 + nj * 16 + lr;
                int tt = m >> 6, bb = m & 63;
                int g = n >> 10, jc = n & 1023;
                xpf[(((size_t)tt * NBLK + (jc >> 3)) * 64 + bb) * 32 + (jc & 7) * 4 + g]
                    = f2bf(acc[mi][nj][r]);
            }
}

// ---------------------------------------------------------------------------
// Persistent MFMA LSTM loop. Round-16: round-15 base + stripe-done release.
// Arrival: fetch_add on own stripe counter (RMW-only lines, never polled).
// Release: stripe completer STORES done[s]=t+1 (store-only lines); wave kq
// polls done[2kq], done[2kq+1] — its exact h-source stripes. Master counter
// and flag-rebroadcast deleted: 2 L3 hops after last arrival instead of 3,
// plus early release pipelines straggler skew into the h-load phase.
// Full-barrier-before-overwrite invariant preserved: the block's 8 waves
// collectively join all 16 stripes, and the next step's reduction
// __syncthreads joins the waves before any h-write.
// ---------------------------------------------------------------------------
__global__ __launch_bounds__(512, 1) void lstm_loop14(
    const unsigned short* __restrict__ xpf,
    const unsigned short* __restrict__ PGh, const unsigned short* __restrict__ PGl,
    const unsigned short* __restrict__ POh, const unsigned short* __restrict__ POl,
    const float* __restrict__ c0,
    unsigned short* __restrict__ hA, unsigned short* __restrict__ hB,
    float* __restrict__ out,
    unsigned* __restrict__ bar)
{
    __shared__ f32x4 red[8][12][64];    // [wave][mt*3+nc][lane]  96 KB
    __shared__ f32x4 redF[12][64];      //                        12 KB

    const int tid  = threadIdx.x;
    const int lane = tid & 63;
    const int kq   = tid >> 6;
    const int ng   = blockIdx.x;        // 0..127

    // ---- persistent B fragments in registers ----
    short8_t bgh[2][4], bgl[2][4], boh[4], bol[4];
#pragma unroll
    for (int i = 0; i < 4; ++i) {
        int ks = 4 * kq + i;
#pragma unroll
        for (int nt = 0; nt < 2; ++nt) {
            size_t og = (((size_t)(ng * 2 + nt) * 32 + ks) * 64 + lane) * 8;
            bgh[nt][i] = *(const short8_t*)(PGh + og);
            bgl[nt][i] = *(const short8_t*)(PGl + og);
        }
        short8_t zh = {0,0,0,0,0,0,0,0};
        short8_t zl = {0,0,0,0,0,0,0,0};
        if ((lane & 15) < 8) {
            size_t oo = (((size_t)ng * 32 + ks) * 32 + (lane >> 4) * 8 + (lane & 7)) * 8;
            zh = *(const short8_t*)(POh + oo);
            zl = *(const short8_t*)(POl + oo);
        }
        boh[i] = zh; bol[i] = zl;
    }

    // combine identity: all 512 threads, b = tid>>3, jj = tid&7
    const int cb = tid >> 3, cjj = tid & 7;
    float c_reg = c0[(size_t)cb * 1024 + 8 * ng + cjj];
    ushort4_t xq = *(const ushort4_t*)(xpf + ((size_t)ng * 64 + cb) * 32 + cjj * 4);

    // h-store address pieces: j-range [8ng,8ng+8) = one full 8-elem k-group
    const int ks2  = ng >> 2;
    const int l2hi = (ng & 3) << 4;
    const unsigned hbase = ((((unsigned)(cb >> 4)) * 32 + ks2) * 64 + ((cb & 15) | l2hi)) * 8 + cjj;

    // barrier lines: stripe counters (RMW-only) at bar + s*32;
    // stripe-done flags (store-only, polled) at bar + 1024 + s*32.
    unsigned* myStripe = bar + (ng >> 3) * 32;
    unsigned* myDone   = bar + 1024 + (ng >> 3) * 32;
    unsigned* done0    = bar + 1024 + (2 * kq)     * 32;
    unsigned* done1    = bar + 1024 + (2 * kq + 1) * 32;

#pragma unroll 1
    for (int t = 0; t <= T_STEPS; ++t) {
        const unsigned short* hc = (t & 1) ? hB : hA;
        unsigned short*       hn = (t & 1) ? hA : hB;

        // ---- hoisted h loads: all 4 k-groups x 4 m-tiles x hi/lo at once ----
        short8_t ah[4][4], al[4][4];
#pragma unroll
        for (int i = 0; i < 4; ++i) {
            const int ks = 4 * kq + i;
#pragma unroll
            for (int mt = 0; mt < 4; ++mt) {
                int off = ((mt * 32 + ks) * 64 + lane) * 8;
                union { short8_t v; unsigned long long q[2]; } uh, ul;
                const unsigned long long* ph = (const unsigned long long*)(hc + off);
                const unsigned long long* pl = (const unsigned long long*)(hc + 65536 + off);
                uh.q[0] = __hip_atomic_load(ph,     __ATOMIC_RELAXED, __HIP_MEMORY_SCOPE_SYSTEM);
                uh.q[1] = __hip_atomic_load(ph + 1, __ATOMIC_RELAXED, __HIP_MEMORY_SCOPE_SYSTEM);
                ul.q[0] = __hip_atomic_load(pl,     __ATOMIC_RELAXED, __HIP_MEMORY_SCOPE_SYSTEM);
                ul.q[1] = __hip_atomic_load(pl + 1, __ATOMIC_RELAXED, __HIP_MEMORY_SCOPE_SYSTEM);
                ah[i][mt] = uh.v;
                al[i][mt] = ul.v;
            }
        }

        f32x4 acc[4][3];
#pragma unroll
        for (int mt = 0; mt < 4; ++mt)
#pragma unroll
            for (int nc = 0; nc < 3; ++nc)
                acc[mt][nc] = (f32x4){0.f, 0.f, 0.f, 0.f};

#pragma unroll
        for (int i = 0; i < 4; ++i) {
#pragma unroll
            for (int mt = 0; mt < 4; ++mt) {
                acc[mt][0] = __builtin_amdgcn_mfma_f32_16x16x32_bf16(ah[i][mt], bgh[0][i], acc[mt][0], 0,0,0);
                acc[mt][1] = __builtin_amdgcn_mfma_f32_16x16x32_bf16(ah[i][mt], bgh[1][i], acc[mt][1], 0,0,0);
                acc[mt][2] = __builtin_amdgcn_mfma_f32_16x16x32_bf16(ah[i][mt], boh[i],    acc[mt][2], 0,0,0);
                acc[mt][0] = __builtin_amdgcn_mfma_f32_16x16x32_bf16(al[i][mt], bgh[0][i], acc[mt][0], 0,0,0);
                acc[mt][1] = __builtin_amdgcn_mfma_f32_16x16x32_bf16(al[i][mt], bgh[1][i], acc[mt][1], 0,0,0);
                acc[mt][2] = __builtin_amdgcn_mfma_f32_16x16x32_bf16(al[i][mt], boh[i],    acc[mt][2], 0,0,0);
                acc[mt][0] = __builtin_amdgcn_mfma_f32_16x16x32_bf16(ah[i][mt], bgl[0][i], acc[mt][0], 0,0,0);
                acc[mt][1] = __builtin_amdgcn_mfma_f32_16x16x32_bf16(ah[i][mt], bgl[1][i], acc[mt][1], 0,0,0);
                acc[mt][2] = __builtin_amdgcn_mfma_f32_16x16x32_bf16(ah[i][mt], bol[i],    acc[mt][2], 0,0,0);
            }
        }

        // ---- K-reduction across 8 waves (12 tiles) ----
#pragma unroll
        for (int mt = 0; mt < 4; ++mt)
#pragma unroll
            for (int nc = 0; nc < 3; ++nc)
                red[kq][mt * 3 + nc][lane] = acc[mt][nc];
        __syncthreads();
        {
            f32x4 s = red[0][kq][lane];
#pragma unroll
            for (int q = 1; q < 8; ++q) s += red[q][kq][lane];
            redF[kq][lane] = s;
        }
        if (kq < 4) {
            const int tl = 8 + kq;
            f32x4 s = red[0][tl][lane];
#pragma unroll
            for (int q = 1; q < 8; ++q) s += red[q][tl][lane];
            redF[tl][lane] = s;
        }
        __syncthreads();

        // ---- combine (all 512 threads): gates -> c,h (direct publish) ----
        float ov;
        {
            const int mt = cb >> 4;
            const int lnb = (cb & 12) << 2;
            const int rg = cb & 3;
            ov = redF[mt * 3 + 2][lnb | cjj][rg];
            if (t < T_STEPS) {
                const int nt = cjj >> 2;
                float pre0 = redF[mt * 3 + nt][lnb | (0  + (cjj & 3))][rg] + bf2f(xq[0]);
                float pre1 = redF[mt * 3 + nt][lnb | (4  + (cjj & 3))][rg] + bf2f(xq[1]);
                float pre2 = redF[mt * 3 + nt][lnb | (8  + (cjj & 3))][rg] + bf2f(xq[2]);
                float pre3 = redF[mt * 3 + nt][lnb | (12 + (cjj & 3))][rg] + bf2f(xq[3]);
                float gi = 1.f / (1.f + expf(-pre0));
                float gf = 1.f / (1.f + expf(-pre1));
                float go = 1.f / (1.f + expf(-pre2));
                float cn = gf * c_reg + gi * tanhf(pre3);
                c_reg = cn;
                float hv = go * tanhf(cn);
                unsigned short hhi = f2bf(hv);
                unsigned short hlo = f2bf(hv - bf2f(hhi));

                // pair-pack with neighbor lane (cjj+1) and publish directly
                unsigned hhiN = (unsigned short)__shfl_down((int)hhi, 1);
                unsigned hloN = (unsigned short)__shfl_down((int)hlo, 1);
                if ((cjj & 1) == 0) {
                    unsigned hp = (unsigned)hhi | (hhiN << 16);
                    unsigned lp = (unsigned)hlo | (hloN << 16);
                    __hip_atomic_store((unsigned*)(hn + hbase), hp,
                                       __ATOMIC_RELAXED, __HIP_MEMORY_SCOPE_SYSTEM);
                    __hip_atomic_store((unsigned*)(hn + hbase + 65536), lp,
                                       __ATOMIC_RELAXED, __HIP_MEMORY_SCOPE_SYSTEM);
                }
            }
        }

        // ---- stripe barrier: RMW arrival; store-only done; 2-stripe poll ----
        if (t < T_STEPS) {
            __syncthreads();   // all waves' h stores drained before arrival
            const unsigned tgt = (unsigned)(t + 1);
            if (tid == 0) {
                unsigned old = __hip_atomic_fetch_add(myStripe, 1u,
                                   __ATOMIC_RELAXED, __HIP_MEMORY_SCOPE_SYSTEM);
                if (old == 8u * tgt - 1u)
                    __hip_atomic_store(myDone, tgt,
                                   __ATOMIC_RELAXED, __HIP_MEMORY_SCOPE_SYSTEM);
            }
            // each wave releases when its two h-source stripes are done
            while (__hip_atomic_load(done0, __ATOMIC_RELAXED, __HIP_MEMORY_SCOPE_SYSTEM) < tgt)
                __builtin_amdgcn_s_sleep(1);
            while (__hip_atomic_load(done1, __ATOMIC_RELAXED, __HIP_MEMORY_SCOPE_SYSTEM) < tgt)
                __builtin_amdgcn_s_sleep(1);
        }

        // ---- post-barrier: xq prefetch for t+1 and out[t-1] write ----
        if (t + 1 < T_STEPS)
            xq = *(const ushort4_t*)(xpf +
                (((size_t)(t + 1) * NBLK + ng) * 64 + cb) * 32 + cjj * 4);
        if (t > 0)
            out[(size_t)(t - 1) * 65536 + cb * 1024 + 8 * ng + cjj] = ov;
    }
}

// ---------------------------------------------------------------------------
extern "C" void kernel_launch(void* const* d_in, const int* in_sizes, int n_in,
                              void* d_out, int out_size, void* d_ws, size_t ws_size,
                              hipStream_t stream)
{
    const float* x    = (const float*)d_in[0];
    const float* h0   = (const float*)d_in[1];
    const float* c0   = (const float*)d_in[2];
    const float* Wxi  = (const float*)d_in[3];
    const float* Wxf  = (const float*)d_in[4];
    const float* Wxo  = (const float*)d_in[5];
    const float* Wxc  = (const float*)d_in[6];
    const float* Whi  = (const float*)d_in[7];
    const float* Whf  = (const float*)d_in[8];
    const float* Who  = (const float*)d_in[9];
    const float* Whc  = (const float*)d_in[10];
    const float* Wout = (const float*)d_in[11];
    float* out = (float*)d_out;

    const size_t PG_B  = (size_t)NBLK * 2 * 32 * 64 * 8 * 2;   //  8,388,608 each
    const size_t PO_B  = (size_t)NBLK * 32 * 32 * 8 * 2;       //  2,097,152 each
    const size_t HF_B  = (size_t)2 * 4 * 32 * 64 * 8 * 2;      //    262,144 each
    const size_t BAR_B = 8192;
    const size_t XPF_B = (size_t)T_STEPS * NBLK * 64 * 32 * 2; // 134,217,728

    char* ws = (char*)d_ws;
    unsigned short* PGh = (unsigned short*)ws;  ws += PG_B;
    unsigned short* PGl = (unsigned short*)ws;  ws += PG_B;
    unsigned short* POh = (unsigned short*)ws;  ws += PO_B;
    unsigned short* POl = (unsigned short*)ws;  ws += PO_B;
    unsigned short* hA  = (unsigned short*)ws;  ws += HF_B;
    unsigned short* hB  = (unsigned short*)ws;  ws += HF_B;
    unsigned*       bar = (unsigned*)ws;        ws += BAR_B;
    unsigned short* xpf = (unsigned short*)ws;  ws += XPF_B;

    hipMemsetAsync(bar, 0, BAR_B, stream);
    pack_gate<<<dim3(16, NBLK), 256, 0, stream>>>(Whi, Whf, Who, Whc, PGh, PGl);
    pack_out<<<dim3(4, NBLK), 256, 0, stream>>>(Wout, POh, POl);
    trans_h0f<<<dim3(64), 256, 0, stream>>>(h0, hA);
    xproj_mfma<<<dim3(128, 32), 256, 0, stream>>>(x, Wxi, Wxf, Wxo, Wxc, xpf);

    lstm_loop14<<<dim3(NBLK), dim3(512), 0, stream>>>(
        xpf, PGh, PGl, POh, POl, c0, hA, hB, out, bar);
}

// Round 17
// 1882.483 us; speedup vs baseline: 1.4193x; 1.3601x over previous
//
#include <hip/hip_runtime.h>
#include <hip/hip_bf16.h>
#include <math.h>

#define T_STEPS 256
#define NBLK    128

typedef __attribute__((ext_vector_type(8))) short short8_t;   // 8 bf16
typedef __attribute__((ext_vector_type(4))) float f32x4;
typedef __attribute__((ext_vector_type(4))) unsigned short ushort4_t;

__device__ __forceinline__ unsigned short f2bf(float v) {
    __hip_bfloat16 h = __float2bfloat16(v);
    return *reinterpret_cast<unsigned short*>(&h);
}
__device__ __forceinline__ float bf2f(unsigned short u) {
    __hip_bfloat16 h;
    *reinterpret_cast<unsigned short*>(&h) = u;
    return __bfloat162float(h);
}

// ---------------------------------------------------------------------------
// pack_gate: gate-weight B-fragments for 128-block layout, bf16 hi/lo.
// ---------------------------------------------------------------------------
__global__ __launch_bounds__(256) void pack_gate(
    const float* __restrict__ Wi, const float* __restrict__ Wf,
    const float* __restrict__ Wo, const float* __restrict__ Wc,
    unsigned short* __restrict__ PGh, unsigned short* __restrict__ PGl)
{
    int ng = blockIdx.y;
    int slot = blockIdx.x * 4 + (threadIdx.x >> 6);   // 0..63
    int nt = slot >> 5, ks = slot & 31;
    int lane = threadIdx.x & 63;
    int n = lane & 15, g = n >> 2;
    int j = 8 * ng + nt * 4 + (n & 3);
    int k0 = ks * 32 + (lane >> 4) * 8;
    const float* W = (g == 0) ? Wi : (g == 1) ? Wf : (g == 2) ? Wo : Wc;
    const float* src = W + (size_t)j * 1024 + k0;

    union { short8_t v; unsigned short u[8]; } hi, lo;
#pragma unroll
    for (int e = 0; e < 8; ++e) {
        float v = src[e];
        hi.u[e] = f2bf(v);
        lo.u[e] = f2bf(v - bf2f(hi.u[e]));
    }
    size_t o = (((size_t)(ng * 2 + nt) * 32 + ks) * 64 + lane) * 8;
    *(short8_t*)(PGh + o) = hi.v;
    *(short8_t*)(PGl + o) = lo.v;
}

// ---------------------------------------------------------------------------
// pack_out: compact out-weight frags (8 real cols per block).
// ---------------------------------------------------------------------------
__global__ __launch_bounds__(256) void pack_out(
    const float* __restrict__ Wout,
    unsigned short* __restrict__ POh, unsigned short* __restrict__ POl)
{
    int ng = blockIdx.y;
    int ks = blockIdx.x * 8 + (threadIdx.x >> 5);
    int sl = threadIdx.x & 31;
    int kb = sl >> 3, n = sl & 7;
    int j = 8 * ng + n;
    int k0 = ks * 32 + kb * 8;
    const float* src = Wout + (size_t)j * 1024 + k0;

    union { short8_t v; unsigned short u[8]; } hi, lo;
#pragma unroll
    for (int e = 0; e < 8; ++e) {
        float v = src[e];
        hi.u[e] = f2bf(v);
        lo.u[e] = f2bf(v - bf2f(hi.u[e]));
    }
    size_t o = (((size_t)ng * 32 + ks) * 32 + sl) * 8;
    *(short8_t*)(POh + o) = hi.v;
    *(short8_t*)(POl + o) = lo.v;
}

// ---------------------------------------------------------------------------
// trans_h0f: h0[b][k] -> A-fragment layout [copy][mt][ks][lane][8] bf16 hi/lo
// (lo copy still written; round-17 loop reads only the hi half.)
// ---------------------------------------------------------------------------
__global__ __launch_bounds__(256) void trans_h0f(
    const float* __restrict__ h0, unsigned short* __restrict__ hA)
{
    int id = blockIdx.x * 256 + threadIdx.x;   // [0, 16384)
    int lane = id & 63;
    int ks = (id >> 6) & 31;
    int mt = (id >> 11) & 3;
    int copy = id >> 13;
    int b = mt * 16 + (lane & 15);
    int k = ks * 32 + (lane >> 4) * 8;
    const float* src = h0 + (size_t)b * 1024 + k;

    union { short8_t v; unsigned short u[8]; } o;
#pragma unroll
    for (int e = 0; e < 8; ++e) {
        float v = src[e];
        unsigned short hb = f2bf(v);
        o.u[e] = (copy == 0) ? hb : f2bf(v - bf2f(hb));
    }
    *(short8_t*)(hA + (size_t)id * 8) = o.v;
}

// ---------------------------------------------------------------------------
// xproj bf16 MFMA GEMM; epilogue scatters to xpf[t][ng(128)][b][jj(8)][g(4)].
// ---------------------------------------------------------------------------
__global__ __launch_bounds__(256) void xproj_mfma(
    const float* __restrict__ X,
    const float* __restrict__ W0, const float* __restrict__ W1,
    const float* __restrict__ W2, const float* __restrict__ W3,
    unsigned short* __restrict__ xpf)
{
    __shared__ short8_t As[4 * 128];
    __shared__ short8_t Bs[4 * 128];

    const int bm = blockIdx.x;
    const int bn = blockIdx.y;
    const float* W = (bn < 8) ? W0 : (bn < 16) ? W1 : (bn < 24) ? W2 : W3;
    const int jbase = (bn & 7) * 128;
    const int m0 = bm * 128;

    const int tid  = threadIdx.x;
    const int lane = tid & 63;
    const int wave = tid >> 6;
    const int wm = wave >> 1, wn = wave & 1;
    const int q  = lane >> 4;
    const int lr = lane & 15;

    f32x4 acc[4][4];
#pragma unroll
    for (int i = 0; i < 4; ++i)
#pragma unroll
        for (int j = 0; j < 4; ++j) acc[i][j] = (f32x4){0.f, 0.f, 0.f, 0.f};

    for (int k0 = 0; k0 < 1024; k0 += 32) {
#pragma unroll
        for (int ss = 0; ss < 2; ++ss) {
            int s  = tid + ss * 256;
            int kg = s & 3, r = s >> 2;
            const float* xa = X + (size_t)(m0 + r) * 1024 + k0 + kg * 8;
            const float* wb = W + (size_t)(jbase + r) * 1024 + k0 + kg * 8;
            float4 a0 = *(const float4*)(xa);
            float4 a1 = *(const float4*)(xa + 4);
            float4 b0 = *(const float4*)(wb);
            float4 b1 = *(const float4*)(wb + 4);
            union { short8_t v; unsigned short u[8]; } ua, ub;
            float af[8] = {a0.x,a0.y,a0.z,a0.w,a1.x,a1.y,a1.z,a1.w};
            float bf[8] = {b0.x,b0.y,b0.z,b0.w,b1.x,b1.y,b1.z,b1.w};
#pragma unroll
            for (int e = 0; e < 8; ++e) {
                ua.u[e] = f2bf(af[e]);
                ub.u[e] = f2bf(bf[e]);
            }
            As[kg * 128 + r] = ua.v;
            Bs[kg * 128 + r] = ub.v;
        }
        __syncthreads();

        short8_t a[4], b[4];
#pragma unroll
        for (int mi = 0; mi < 4; ++mi)
            a[mi] = As[q * 128 + wm * 64 + mi * 16 + lr];
#pragma unroll
        for (int nj = 0; nj < 4; ++nj)
            b[nj] = Bs[q * 128 + wn * 64 + nj * 16 + lr];
#pragma unroll
        for (int mi = 0; mi < 4; ++mi)
#pragma unroll
            for (int nj = 0; nj < 4; ++nj)
                acc[mi][nj] = __builtin_amdgcn_mfma_f32_16x16x32_bf16(
                    a[mi], b[nj], acc[mi][nj], 0, 0, 0);
        __syncthreads();
    }

#pragma unroll
    for (int mi = 0; mi < 4; ++mi)
#pragma unroll
        for (int nj = 0; nj < 4; ++nj)
#pragma unroll
            for (int r = 0; r < 4; ++r) {
                int m = m0 + wm * 64 + mi * 16 + q * 4 + r;
                int n = bn * 128 + wn * 64 + nj * 16 + lr;
                int tt = m >> 6, bb = m & 63;
                int g = n >> 10, jc = n & 1023;
                xpf[(((size_t)tt * NBLK + (jc >> 3)) * 64 + bb) * 32 + (jc & 7) * 4 + g]
                    = f2bf(acc[mi][nj][r]);
            }
}

// ---------------------------------------------------------------------------
// Persistent MFMA LSTM loop. Round-17 = round-16 structure + bf16-only h
// exchange: drop the h-lo stream (loads, MFMAs, publish). Weight hi/lo kept
// (register-resident, no traffic). Halves the per-step L3 h broadcast
// (32 -> 16 MB) and cuts MFMA 9 -> 6 per (i,mt).
// ---------------------------------------------------------------------------
__global__ __launch_bounds__(512, 1) void lstm_loop15(
    const unsigned short* __restrict__ xpf,
    const unsigned short* __restrict__ PGh, const unsigned short* __restrict__ PGl,
    const unsigned short* __restrict__ POh, const unsigned short* __restrict__ POl,
    const float* __restrict__ c0,
    unsigned short* __restrict__ hA, unsigned short* __restrict__ hB,
    float* __restrict__ out,
    unsigned* __restrict__ bar)
{
    __shared__ f32x4 red[8][12][64];    // [wave][mt*3+nc][lane]  96 KB
    __shared__ f32x4 redF[12][64];      //                        12 KB

    const int tid  = threadIdx.x;
    const int lane = tid & 63;
    const int kq   = tid >> 6;
    const int ng   = blockIdx.x;        // 0..127

    // ---- persistent B fragments in registers ----
    short8_t bgh[2][4], bgl[2][4], boh[4], bol[4];
#pragma unroll
    for (int i = 0; i < 4; ++i) {
        int ks = 4 * kq + i;
#pragma unroll
        for (int nt = 0; nt < 2; ++nt) {
            size_t og = (((size_t)(ng * 2 + nt) * 32 + ks) * 64 + lane) * 8;
            bgh[nt][i] = *(const short8_t*)(PGh + og);
            bgl[nt][i] = *(const short8_t*)(PGl + og);
        }
        short8_t zh = {0,0,0,0,0,0,0,0};
        short8_t zl = {0,0,0,0,0,0,0,0};
        if ((lane & 15) < 8) {
            size_t oo = (((size_t)ng * 32 + ks) * 32 + (lane >> 4) * 8 + (lane & 7)) * 8;
            zh = *(const short8_t*)(POh + oo);
            zl = *(const short8_t*)(POl + oo);
        }
        boh[i] = zh; bol[i] = zl;
    }

    // combine identity: all 512 threads, b = tid>>3, jj = tid&7
    const int cb = tid >> 3, cjj = tid & 7;
    float c_reg = c0[(size_t)cb * 1024 + 8 * ng + cjj];
    ushort4_t xq = *(const ushort4_t*)(xpf + ((size_t)ng * 64 + cb) * 32 + cjj * 4);

    // h-store address pieces: j-range [8ng,8ng+8) = one full 8-elem k-group
    const int ks2  = ng >> 2;
    const int l2hi = (ng & 3) << 4;
    const unsigned hbase = ((((unsigned)(cb >> 4)) * 32 + ks2) * 64 + ((cb & 15) | l2hi)) * 8 + cjj;

    // barrier lines: stripe counters (RMW-only) at bar + s*32;
    // stripe-done flags (store-only, polled) at bar + 1024 + s*32.
    unsigned* myStripe = bar + (ng >> 3) * 32;
    unsigned* myDone   = bar + 1024 + (ng >> 3) * 32;
    unsigned* done0    = bar + 1024 + (2 * kq)     * 32;
    unsigned* done1    = bar + 1024 + (2 * kq + 1) * 32;

#pragma unroll 1
    for (int t = 0; t <= T_STEPS; ++t) {
        const unsigned short* hc = (t & 1) ? hB : hA;
        unsigned short*       hn = (t & 1) ? hA : hB;

        // ---- hoisted h loads (hi only): 4 k-groups x 4 m-tiles at once ----
        short8_t ah[4][4];
#pragma unroll
        for (int i = 0; i < 4; ++i) {
            const int ks = 4 * kq + i;
#pragma unroll
            for (int mt = 0; mt < 4; ++mt) {
                int off = ((mt * 32 + ks) * 64 + lane) * 8;
                union { short8_t v; unsigned long long q[2]; } uh;
                const unsigned long long* ph = (const unsigned long long*)(hc + off);
                uh.q[0] = __hip_atomic_load(ph,     __ATOMIC_RELAXED, __HIP_MEMORY_SCOPE_SYSTEM);
                uh.q[1] = __hip_atomic_load(ph + 1, __ATOMIC_RELAXED, __HIP_MEMORY_SCOPE_SYSTEM);
                ah[i][mt] = uh.v;
            }
        }

        f32x4 acc[4][3];
#pragma unroll
        for (int mt = 0; mt < 4; ++mt)
#pragma unroll
            for (int nc = 0; nc < 3; ++nc)
                acc[mt][nc] = (f32x4){0.f, 0.f, 0.f, 0.f};

#pragma unroll
        for (int i = 0; i < 4; ++i) {
#pragma unroll
            for (int mt = 0; mt < 4; ++mt) {
                acc[mt][0] = __builtin_amdgcn_mfma_f32_16x16x32_bf16(ah[i][mt], bgh[0][i], acc[mt][0], 0,0,0);
                acc[mt][1] = __builtin_amdgcn_mfma_f32_16x16x32_bf16(ah[i][mt], bgh[1][i], acc[mt][1], 0,0,0);
                acc[mt][2] = __builtin_amdgcn_mfma_f32_16x16x32_bf16(ah[i][mt], boh[i],    acc[mt][2], 0,0,0);
                acc[mt][0] = __builtin_amdgcn_mfma_f32_16x16x32_bf16(ah[i][mt], bgl[0][i], acc[mt][0], 0,0,0);
                acc[mt][1] = __builtin_amdgcn_mfma_f32_16x16x32_bf16(ah[i][mt], bgl[1][i], acc[mt][1], 0,0,0);
                acc[mt][2] = __builtin_amdgcn_mfma_f32_16x16x32_bf16(ah[i][mt], bol[i],    acc[mt][2], 0,0,0);
            }
        }

        // ---- K-reduction across 8 waves (12 tiles) ----
#pragma unroll
        for (int mt = 0; mt < 4; ++mt)
#pragma unroll
            for (int nc = 0; nc < 3; ++nc)
                red[kq][mt * 3 + nc][lane] = acc[mt][nc];
        __syncthreads();
        {
            f32x4 s = red[0][kq][lane];
#pragma unroll
            for (int q = 1; q < 8; ++q) s += red[q][kq][lane];
            redF[kq][lane] = s;
        }
        if (kq < 4) {
            const int tl = 8 + kq;
            f32x4 s = red[0][tl][lane];
#pragma unroll
            for (int q = 1; q < 8; ++q) s += red[q][tl][lane];
            redF[tl][lane] = s;
        }
        __syncthreads();

        // ---- combine (all 512 threads): gates -> c,h (direct publish) ----
        float ov;
        {
            const int mt = cb >> 4;
            const int lnb = (cb & 12) << 2;
            const int rg = cb & 3;
            ov = redF[mt * 3 + 2][lnb | cjj][rg];
            if (t < T_STEPS) {
                const int nt = cjj >> 2;
                float pre0 = redF[mt * 3 + nt][lnb | (0  + (cjj & 3))][rg] + bf2f(xq[0]);
                float pre1 = redF[mt * 3 + nt][lnb | (4  + (cjj & 3))][rg] + bf2f(xq[1]);
                float pre2 = redF[mt * 3 + nt][lnb | (8  + (cjj & 3))][rg] + bf2f(xq[2]);
                float pre3 = redF[mt * 3 + nt][lnb | (12 + (cjj & 3))][rg] + bf2f(xq[3]);
                float gi = 1.f / (1.f + expf(-pre0));
                float gf = 1.f / (1.f + expf(-pre1));
                float go = 1.f / (1.f + expf(-pre2));
                float cn = gf * c_reg + gi * tanhf(pre3);
                c_reg = cn;
                float hv = go * tanhf(cn);
                unsigned short hhi = f2bf(hv);

                // pair-pack with neighbor lane (cjj+1) and publish (hi only)
                unsigned hhiN = (unsigned short)__shfl_down((int)hhi, 1);
                if ((cjj & 1) == 0) {
                    unsigned hp = (unsigned)hhi | (hhiN << 16);
                    __hip_atomic_store((unsigned*)(hn + hbase), hp,
                                       __ATOMIC_RELAXED, __HIP_MEMORY_SCOPE_SYSTEM);
                }
            }
        }

        // ---- stripe barrier: RMW arrival; store-only done; 2-stripe poll ----
        if (t < T_STEPS) {
            __syncthreads();   // all waves' h stores drained before arrival
            const unsigned tgt = (unsigned)(t + 1);
            if (tid == 0) {
                unsigned old = __hip_atomic_fetch_add(myStripe, 1u,
                                   __ATOMIC_RELAXED, __HIP_MEMORY_SCOPE_SYSTEM);
                if (old == 8u * tgt - 1u)
                    __hip_atomic_store(myDone, tgt,
                                   __ATOMIC_RELAXED, __HIP_MEMORY_SCOPE_SYSTEM);
            }
            // each wave releases when its two h-source stripes are done
            while (__hip_atomic_load(done0, __ATOMIC_RELAXED, __HIP_MEMORY_SCOPE_SYSTEM) < tgt)
                __builtin_amdgcn_s_sleep(1);
            while (__hip_atomic_load(done1, __ATOMIC_RELAXED, __HIP_MEMORY_SCOPE_SYSTEM) < tgt)
                __builtin_amdgcn_s_sleep(1);
        }

        // ---- post-barrier: xq prefetch for t+1 and out[t-1] write ----
        if (t + 1 < T_STEPS)
            xq = *(const ushort4_t*)(xpf +
                (((size_t)(t + 1) * NBLK + ng) * 64 + cb) * 32 + cjj * 4);
        if (t > 0)
            out[(size_t)(t - 1) * 65536 + cb * 1024 + 8 * ng + cjj] = ov;
    }
}

// ---------------------------------------------------------------------------
extern "C" void kernel_launch(void* const* d_in, const int* in_sizes, int n_in,
                              void* d_out, int out_size, void* d_ws, size_t ws_size,
                              hipStream_t stream)
{
    const float* x    = (const float*)d_in[0];
    const float* h0   = (const float*)d_in[1];
    const float* c0   = (const float*)d_in[2];
    const float* Wxi  = (const float*)d_in[3];
    const float* Wxf  = (const float*)d_in[4];
    const float* Wxo  = (const float*)d_in[5];
    const float* Wxc  = (const float*)d_in[6];
    const float* Whi  = (const float*)d_in[7];
    const float* Whf  = (const float*)d_in[8];
    const float* Who  = (const float*)d_in[9];
    const float* Whc  = (const float*)d_in[10];
    const float* Wout = (const float*)d_in[11];
    float* out = (float*)d_out;

    const size_t PG_B  = (size_t)NBLK * 2 * 32 * 64 * 8 * 2;   //  8,388,608 each
    const size_t PO_B  = (size_t)NBLK * 32 * 32 * 8 * 2;       //  2,097,152 each
    const size_t HF_B  = (size_t)2 * 4 * 32 * 64 * 8 * 2;      //    262,144 each
    const size_t BAR_B = 8192;
    const size_t XPF_B = (size_t)T_STEPS * NBLK * 64 * 32 * 2; // 134,217,728

    char* ws = (char*)d_ws;
    unsigned short* PGh = (unsigned short*)ws;  ws += PG_B;
    unsigned short* PGl = (unsigned short*)ws;  ws += PG_B;
    unsigned short* POh = (unsigned short*)ws;  ws += PO_B;
    unsigned short* POl = (unsigned short*)ws;  ws += PO_B;
    unsigned short* hA  = (unsigned short*)ws;  ws += HF_B;
    unsigned short* hB  = (unsigned short*)ws;  ws += HF_B;
    unsigned*       bar = (unsigned*)ws;        ws += BAR_B;
    unsigned short* xpf = (unsigned short*)ws;  ws += XPF_B;

    hipMemsetAsync(bar, 0, BAR_B, stream);
    pack_gate<<<dim3(16, NBLK), 256, 0, stream>>>(Whi, Whf, Who, Whc, PGh, PGl);
    pack_out<<<dim3(4, NBLK), 256, 0, stream>>>(Wout, POh, POl);
    trans_h0f<<<dim3(64), 256, 0, stream>>>(h0, hA);
    xproj_mfma<<<dim3(128, 32), 256, 0, stream>>>(x, Wxi, Wxf, Wxo, Wxc, xpf);

    lstm_loop15<<<dim3(NBLK), dim3(512), 0, stream>>>(
        xpf, PGh, PGl, POh, POl, c0, hA, hB, out, bar);
}